// Round 5
// baseline (320.086 us; speedup 1.0000x reference)
//
#include <hip/hip_runtime.h>

#define E_ 16
#define DIN 256
#define DH 512
#define DOUT 256
#define BTOK 32768

typedef _Float16 half8 __attribute__((ext_vector_type(8)));
typedef _Float16 half4v __attribute__((ext_vector_type(4)));
typedef float float4v __attribute__((ext_vector_type(4)));

// ---------------- workspace layout (bytes) ----------------
#define OFF_P1      0u            // packed W1 fp16: 4 MB
#define OFF_P2      4194304u      // packed W2 fp16: 4 MB
#define OFF_XH      8388608u      // x fp16: 16 MB
#define OFF_SCR     25165824u     // per-assignment weighted out fp16: 32 MB
#define OFF_TIDX    58720256u     // int[B*2]
#define OFF_TW      58982400u     // float[B*2]
#define OFF_STOK    59244544u     // int[65536]: g = tok*2+slot per sorted assignment
#define OFF_SW      59506688u     // float[65536]
#define OFF_CNT     59768832u     // int[16]
#define OFF_OFFS    59768960u     // int[17]
#define OFF_CUR     59769088u     // int[16]
#define OFF_TMAP    59769216u     // int[2048] blockIdx -> (e<<16)|tile_in_e, -1 = idle
#define MLP_GRID    2048          // 8 XCD lanes x 256 slots (worst-case safe)

// ---------------- pack W1/W2 into MFMA fragment layout (fp16); zero counts ----------------
// frag (16x16x32): lane l holds M[k = (l>>4)*8 + j][n = (l&15)] per 32x16 tile
__global__ __launch_bounds__(256) void pack_kernel(const float* __restrict__ W1,
                                                   const float* __restrict__ W2,
                                                   _Float16* __restrict__ p1,
                                                   _Float16* __restrict__ p2,
                                                   int* __restrict__ counts) {
    int tid = threadIdx.x;
    int bid = blockIdx.x * 4 + (tid >> 6);
    int l = tid & 63;
    int quad = l >> 4, l15 = l & 15;
    if (blockIdx.x == 0 && tid < 16) counts[tid] = 0;
    if (bid < 4096) {              // W1: bid = (e*8 + kt)*32 + ht
        int ht = bid & 31, kt = (bid >> 5) & 7, e = bid >> 8;
        half8 v;
#pragma unroll
        for (int j = 0; j < 8; ++j)
            v[j] = (_Float16)W1[(e * DIN + kt * 32 + quad * 8 + j) * DH + ht * 16 + l15];
        ((half8*)p1)[bid * 64 + l] = v;
    } else {                       // W2: bid-4096 = (e*16 + kt2)*16 + ot
        int b2i = bid - 4096;
        int ot = b2i & 15, kt = (b2i >> 4) & 15, e = b2i >> 8;
        half8 v;
#pragma unroll
        for (int j = 0; j < 8; ++j)
            v[j] = (_Float16)W2[(e * DH + kt * 32 + quad * 8 + j) * DOUT + ot * 16 + l15];
        ((half8*)p2)[b2i * 64 + l] = v;
    }
}

// ---------------- gating (fp32) + x->fp16 conversion, fused ----------------
__global__ __launch_bounds__(256) void gate_kernel(const float* __restrict__ x,
                                                   const float* __restrict__ Wg,
                                                   const float* __restrict__ bg,
                                                   _Float16* __restrict__ xh,
                                                   int* __restrict__ tidx,
                                                   float* __restrict__ tw,
                                                   int* __restrict__ counts) {
    __shared__ float WgS[DIN * E_];                   // 16 KB
    __shared__ int hcnt[16];
    int tid = threadIdx.x;
    if (tid < 16) hcnt[tid] = 0;
#pragma unroll
    for (int i = 0; i < 4; ++i)
        ((float4v*)WgS)[tid + i * 256] = ((const float4v*)Wg)[tid + i * 256];
    __syncthreads();

    int q = tid & 7, tg = tid >> 3;                   // 32 groups x 2 tokens = 64 tokens/block
    int t0 = blockIdx.x * 64 + tg * 2;

    float acc[2][16];
#pragma unroll
    for (int tt = 0; tt < 2; ++tt)
#pragma unroll
        for (int e = 0; e < 16; ++e) acc[tt][e] = 0.f;

#pragma unroll
    for (int ii = 0; ii < 8; ++ii) {                  // K-eighth: 32 floats = 8 float4
        int kb = q * 32 + ii * 4;
        float4v xv[2];
#pragma unroll
        for (int tt = 0; tt < 2; ++tt) {
            xv[tt] = *(const float4v*)&x[(t0 + tt) * DIN + kb];
            half4v hv;
#pragma unroll
            for (int j = 0; j < 4; ++j) hv[j] = (_Float16)xv[tt][j];
            *(half4v*)&xh[(t0 + tt) * DIN + kb] = hv;
        }
#pragma unroll
        for (int j = 0; j < 4; ++j) {
            const float4v* wrow = (const float4v*)&WgS[(kb + j) * 16];
            float4v w0 = wrow[0], w1 = wrow[1], w2 = wrow[2], w3 = wrow[3];
#pragma unroll
            for (int tt = 0; tt < 2; ++tt) {
                float xs = xv[tt][j];
#pragma unroll
                for (int c = 0; c < 4; ++c) {
                    acc[tt][0 + c]  += xs * w0[c];
                    acc[tt][4 + c]  += xs * w1[c];
                    acc[tt][8 + c]  += xs * w2[c];
                    acc[tt][12 + c] += xs * w3[c];
                }
            }
        }
    }
#pragma unroll
    for (int tt = 0; tt < 2; ++tt)
#pragma unroll
        for (int e = 0; e < 16; ++e) {
            acc[tt][e] += __shfl_xor(acc[tt][e], 1);
            acc[tt][e] += __shfl_xor(acc[tt][e], 2);
            acc[tt][e] += __shfl_xor(acc[tt][e], 4);
        }
    if (q == 0) {
#pragma unroll
        for (int tt = 0; tt < 2; ++tt) {
            int b = t0 + tt;
            float m1 = -3.4e38f, m2 = -3.4e38f;
            int i1 = 0, i2 = 0;
#pragma unroll
            for (int e = 0; e < 16; ++e) {
                float v = acc[tt][e] + bg[e];
                if (v > m1) { m2 = m1; i2 = i1; m1 = v; i1 = e; }
                else if (v > m2) { m2 = v; i2 = e; }
            }
            float e2 = __expf(m2 - m1);
            float w1 = 1.f / (1.f + e2);
            tidx[b * 2] = i1; tidx[b * 2 + 1] = i2;
            tw[b * 2] = w1;  tw[b * 2 + 1] = e2 * w1;
            atomicAdd(&hcnt[i1], 1);
            atomicAdd(&hcnt[i2], 1);
        }
    }
    __syncthreads();
    if (tid < 16) atomicAdd(&counts[tid], hcnt[tid]);
}

// ---------------- scan + XCD-affine tile map ----------------
// expert e's tiles land at blockIdx ≡ e (mod 8); 256 slots per XCD lane (worst-case safe)
__global__ void scan_kernel(const int* __restrict__ counts, int* __restrict__ offsets,
                            int* __restrict__ cursor, int* __restrict__ tmap) {
    int tid = threadIdx.x;
    for (int i = tid; i < MLP_GRID; i += 64) tmap[i] = -1;
    __syncthreads();
    if (tid == 0) {
        int run = 0;
        int xslot[8];
        for (int xc = 0; xc < 8; ++xc) xslot[xc] = 0;
        for (int e = 0; e < 16; ++e) {
            int c = counts[e];
            offsets[e] = run; cursor[e] = run; run += c;
            int nt = (c + 63) >> 6;
            int xc = e & 7;
            for (int t = 0; t < nt; ++t) {
                int s = xslot[xc]++;
                if (s < 256) tmap[xc + 8 * s] = (e << 16) | t;
            }
        }
        offsets[16] = run;
    }
}

// ---------------- scatter: block-ranked, 16 global atomics per block ----------------
__global__ __launch_bounds__(256) void scatter_kernel(const int* __restrict__ tidx,
                                                      const float* __restrict__ tw,
                                                      int* __restrict__ cursor,
                                                      int* __restrict__ stok,
                                                      float* __restrict__ sw) {
    __shared__ int lc[16];
    __shared__ int lbase[16];
    int tid = threadIdx.x;
    if (tid < 16) lc[tid] = 0;
    __syncthreads();
    int g = blockIdx.x * 256 + tid;
    int e = tidx[g];
    int rank = atomicAdd(&lc[e], 1);
    __syncthreads();
    if (tid < 16) lbase[tid] = atomicAdd(&cursor[tid], lc[tid]);
    __syncthreads();
    int pos = lbase[e] + rank;
    stok[pos] = g;                 // g = tok*2 + slot
    sw[pos] = tw[g];
}

// ---------------- fused expert MLP ----------------
// LDS: Xs 64x256 halfs (32 KB, swizzled) + Hs 64x256 halfs (32 KB, swizzled) = 64 KB
// Phase 1/2 split over two DH-halves; X staged once; weights stream from XCD-local L2.
#define XS 0
#define HS 16384
__global__ __launch_bounds__(512, 4) void mlp_kernel(const _Float16* __restrict__ xh,
                                                     const _Float16* __restrict__ p1,
                                                     const _Float16* __restrict__ p2,
                                                     const float* __restrict__ b1,
                                                     const float* __restrict__ b2,
                                                     const int* __restrict__ offsets,
                                                     const int* __restrict__ stok,
                                                     const float* __restrict__ sw,
                                                     const int* __restrict__ tmap,
                                                     _Float16* __restrict__ scr) {
    __shared__ _Float16 S[32768];                     // 64 KB
    const int tile = tmap[blockIdx.x];
    if (tile < 0) return;
    const int e = tile >> 16;
    const int ts = (tile & 0xffff) * 64;
    const int off = offsets[e];
    const int ne = offsets[e + 1] - off;
    const int rows = min(64, ne - ts);

    const int tid = threadIdx.x;
    const int w = tid >> 6;                           // wave 0..7
    const int l = tid & 63;
    const int l15 = l & 15;
    const int quad = l >> 4;

    // ---- stage X tile (64 tok x 256 halfs) into LDS, 16B-granule XOR swizzle ----
#pragma unroll
    for (int j = 0; j < 4; ++j) {
        int tokl = w * 8 + j * 2 + (l >> 5);          // local token row
        int slot = l & 31;                            // 16B slot within row
        int g = slot ^ (tokl & 7);                    // logical k-granule stored here
        int r = tokl; if (r >= rows) r = rows - 1;
        int tok = stok[off + ts + r] >> 1;
        half8 v = *(const half8*)&xh[tok * DIN + g * 8];
        *(half8*)&S[XS + tokl * 256 + slot * 8] = v;
    }

    const half8* p1b = (const half8*)p1;
    const half8* p2b = (const half8*)p2;

    float4v acc2[4][2];
#pragma unroll
    for (int mt = 0; mt < 4; ++mt)
#pragma unroll
        for (int n = 0; n < 2; ++n) acc2[mt][n] = (float4v){0.f, 0.f, 0.f, 0.f};

    __syncthreads();

#pragma unroll
    for (int half = 0; half < 2; ++half) {
        // ---- phase 1: H[:, half*256 .. half*256+255] ; wave w owns h-tiles w*2, w*2+1 ----
        float4v acc1[2][4];
#pragma unroll
        for (int mh = 0; mh < 2; ++mh)
#pragma unroll
            for (int nt = 0; nt < 4; ++nt) acc1[mh][nt] = (float4v){0.f, 0.f, 0.f, 0.f};

#pragma unroll
        for (int kt = 0; kt < 8; ++kt) {
            half8 bq[4];
#pragma unroll
            for (int nt = 0; nt < 4; ++nt) {
                int row = nt * 16 + l15;
                int slot = (kt * 4 + quad) ^ (l15 & 7);
                bq[nt] = *(const half8*)&S[XS + row * 256 + slot * 8];
            }
#pragma unroll
            for (int mh = 0; mh < 2; ++mh) {
                half8 aw = p1b[((e * 8 + kt) * 32 + half * 16 + w * 2 + mh) * 64 + l];
#pragma unroll
                for (int nt = 0; nt < 4; ++nt)
                    acc1[mh][nt] = __builtin_amdgcn_mfma_f32_16x16x32_f16(aw, bq[nt], acc1[mh][nt], 0, 0, 0);
            }
        }
        // bias + relu + store H-half (half4 per acc tile, swizzled)
#pragma unroll
        for (int mh = 0; mh < 2; ++mh) {
            int colh = (w * 2 + mh) * 16 + quad * 4;  // local h col (0..255)
            float4v b1q = *(const float4v*)&b1[e * DH + half * 256 + colh];
            int gq = colh >> 3;                       // 16B granule
            int go = (quad & 1) * 4;                  // half offset within granule
#pragma unroll
            for (int nt = 0; nt < 4; ++nt) {
                int row = nt * 16 + l15;
                int slot = gq ^ (l15 & 7);
                half4v hv;
#pragma unroll
                for (int r = 0; r < 4; ++r) {
                    float v = acc1[mh][nt][r] + b1q[r];
                    hv[r] = (_Float16)(v > 0.f ? v : 0.f);
                }
                *(half4v*)&S[HS + row * 256 + slot * 8 + go] = hv;
            }
        }
        __syncthreads();

        // ---- phase 2 partial: acc2 += H_half @ W2[half*256.., :] ----
#pragma unroll
        for (int kt2 = 0; kt2 < 8; ++kt2) {
            half8 ha[4];
#pragma unroll
            for (int mt = 0; mt < 4; ++mt) {
                int row = mt * 16 + l15;
                int slot = (kt2 * 4 + quad) ^ (l15 & 7);
                ha[mt] = *(const half8*)&S[HS + row * 256 + slot * 8];
            }
#pragma unroll
            for (int n = 0; n < 2; ++n) {
                half8 bw = p2b[((e * 16 + half * 8 + kt2) * 16 + w * 2 + n) * 64 + l];
#pragma unroll
                for (int mt = 0; mt < 4; ++mt)
                    acc2[mt][n] = __builtin_amdgcn_mfma_f32_16x16x32_f16(ha[mt], bw, acc2[mt][n], 0, 0, 0);
            }
        }
        __syncthreads();                              // H reads done before overwrite / reuse
    }

    // ---- epilogue: +b2, routing weight, transpose through LDS (reuse Hs), coalesced store ----
    float b2v[2];
#pragma unroll
    for (int n = 0; n < 2; ++n) b2v[n] = b2[e * DOUT + (w * 2 + n) * 16 + l15];
#pragma unroll
    for (int mt = 0; mt < 4; ++mt) {
#pragma unroll
        for (int r = 0; r < 4; ++r) {
            int row = mt * 16 + quad * 4 + r;         // token row of this acc element
            int rc = row < rows ? row : rows - 1;
            float wt = sw[off + ts + rc];
#pragma unroll
            for (int n = 0; n < 2; ++n) {
                int col = (w * 2 + n) * 16 + l15;     // out col 0..255
                int slot = (col >> 3) ^ (row & 7);
                S[HS + row * 256 + slot * 8 + (col & 7)] =
                    (_Float16)(wt * (acc2[mt][n][r] + b2v[n]));
            }
        }
    }
    __syncthreads();
#pragma unroll
    for (int p = 0; p < 4; ++p) {
        int idx = p * 512 + tid;
        int tok = idx >> 5;                           // local token row
        int sl = idx & 31;                            // logical 16B granule
        if (tok < rows) {
            int slot = sl ^ (tok & 7);
            half8 v = *(const half8*)&S[HS + tok * 256 + slot * 8];
            int g = stok[off + ts + tok];             // assignment slot = tok*2+sel
            *(half8*)&scr[g * DOUT + sl * 8] = v;
        }
    }
}

// ---------------- combine: out[t] = scr[t*2] + scr[t*2+1], streaming ----------------
__global__ __launch_bounds__(256) void combine_kernel(const _Float16* __restrict__ scr,
                                                      float* __restrict__ out) {
    int wv = threadIdx.x >> 6;
    int l = threadIdx.x & 63;
    int t = blockIdx.x * 4 + wv;
    half4v a = ((const half4v*)(scr + t * 2 * DOUT))[l];
    half4v b = ((const half4v*)(scr + t * 2 * DOUT + DOUT))[l];
    float4v o;
#pragma unroll
    for (int j = 0; j < 4; ++j) o[j] = (float)a[j] + (float)b[j];
    ((float4v*)(out + t * DOUT))[l] = o;
}

extern "C" void kernel_launch(void* const* d_in, const int* in_sizes, int n_in,
                              void* d_out, int out_size, void* d_ws, size_t ws_size,
                              hipStream_t stream) {
    const float* x  = (const float*)d_in[0];
    const float* Wg = (const float*)d_in[1];
    const float* bg = (const float*)d_in[2];
    const float* W1 = (const float*)d_in[3];
    const float* b1 = (const float*)d_in[4];
    const float* W2 = (const float*)d_in[5];
    const float* b2 = (const float*)d_in[6];
    float* out = (float*)d_out;

    char* ws = (char*)d_ws;
    _Float16* p1  = (_Float16*)(ws + OFF_P1);
    _Float16* p2  = (_Float16*)(ws + OFF_P2);
    _Float16* xh  = (_Float16*)(ws + OFF_XH);
    _Float16* scr = (_Float16*)(ws + OFF_SCR);
    int* tidx     = (int*)(ws + OFF_TIDX);
    float* tw     = (float*)(ws + OFF_TW);
    int* stok     = (int*)(ws + OFF_STOK);
    float* swp    = (float*)(ws + OFF_SW);
    int* counts   = (int*)(ws + OFF_CNT);
    int* offsets  = (int*)(ws + OFF_OFFS);
    int* cursor   = (int*)(ws + OFF_CUR);
    int* tmap     = (int*)(ws + OFF_TMAP);

    pack_kernel<<<dim3(2048), dim3(256), 0, stream>>>(W1, W2, p1, p2, counts);
    gate_kernel<<<dim3(512), dim3(256), 0, stream>>>(x, Wg, bg, xh, tidx, tw, counts);
    scan_kernel<<<dim3(1), dim3(64), 0, stream>>>(counts, offsets, cursor, tmap);
    scatter_kernel<<<dim3(256), dim3(256), 0, stream>>>(tidx, tw, cursor, stok, swp);
    mlp_kernel<<<dim3(MLP_GRID), dim3(512), 0, stream>>>(xh, p1, p2, b1, b2, offsets,
                                                         stok, swp, tmap, scr);
    combine_kernel<<<dim3(8192), dim3(256), 0, stream>>>(scr, out);
}

// Round 6
// 220.696 us; speedup vs baseline: 1.4503x; 1.4503x over previous
//
#include <hip/hip_runtime.h>

#define E_ 16
#define DIN 256
#define DH 512
#define DOUT 256
#define BTOK 32768

typedef _Float16 half8 __attribute__((ext_vector_type(8)));
typedef _Float16 half4v __attribute__((ext_vector_type(4)));
typedef float float4v __attribute__((ext_vector_type(4)));

// ---------------- workspace layout (bytes) ----------------
#define OFF_P1      0u            // packed W1 fp16: 4 MB
#define OFF_P2      4194304u      // packed W2 fp16: 4 MB
#define OFF_XH      8388608u      // x fp16: 16 MB
#define OFF_SCR     25165824u     // per-assignment weighted out fp16: 32 MB
#define OFF_TIDX    58720256u     // int[B*2]
#define OFF_TW      58982400u     // float[B*2]
#define OFF_STOK    59244544u     // int[65536]: g = tok*2+slot per sorted assignment
#define OFF_SW      59506688u     // float[65536]
#define OFF_CNT     59768832u     // int[16]
#define OFF_OFFS    59768960u     // int[17]
#define OFF_CUR     59769088u     // int[16]
#define OFF_TMAP    59769216u     // int[2048] blockIdx -> (e<<16)|tile_in_e, -1 = idle
#define MLP_GRID    2048          // 8 XCD lanes x 256 slots (worst-case safe)

// ---------------- pack W1/W2 into MFMA fragment layout (fp16); zero counts ----------------
// frag (16x16x32): lane l holds M[k = (l>>4)*8 + j][n = (l&15)] per 32x16 tile
__global__ __launch_bounds__(256) void pack_kernel(const float* __restrict__ W1,
                                                   const float* __restrict__ W2,
                                                   _Float16* __restrict__ p1,
                                                   _Float16* __restrict__ p2,
                                                   int* __restrict__ counts) {
    int tid = threadIdx.x;
    int bid = blockIdx.x * 4 + (tid >> 6);
    int l = tid & 63;
    int quad = l >> 4, l15 = l & 15;
    if (blockIdx.x == 0 && tid < 16) counts[tid] = 0;
    if (bid < 4096) {              // W1: bid = (e*8 + kt)*32 + ht
        int ht = bid & 31, kt = (bid >> 5) & 7, e = bid >> 8;
        half8 v;
#pragma unroll
        for (int j = 0; j < 8; ++j)
            v[j] = (_Float16)W1[(e * DIN + kt * 32 + quad * 8 + j) * DH + ht * 16 + l15];
        ((half8*)p1)[bid * 64 + l] = v;
    } else {                       // W2: bid-4096 = (e*16 + kt2)*16 + ot
        int b2i = bid - 4096;
        int ot = b2i & 15, kt = (b2i >> 4) & 15, e = b2i >> 8;
        half8 v;
#pragma unroll
        for (int j = 0; j < 8; ++j)
            v[j] = (_Float16)W2[(e * DH + kt * 32 + quad * 8 + j) * DOUT + ot * 16 + l15];
        ((half8*)p2)[b2i * 64 + l] = v;
    }
}

// ---------------- gating (fp32) + x->fp16 conversion, fused ----------------
__global__ __launch_bounds__(256) void gate_kernel(const float* __restrict__ x,
                                                   const float* __restrict__ Wg,
                                                   const float* __restrict__ bg,
                                                   _Float16* __restrict__ xh,
                                                   int* __restrict__ tidx,
                                                   float* __restrict__ tw,
                                                   int* __restrict__ counts) {
    __shared__ float WgS[DIN * E_];                   // 16 KB
    __shared__ int hcnt[16];
    int tid = threadIdx.x;
    if (tid < 16) hcnt[tid] = 0;
#pragma unroll
    for (int i = 0; i < 4; ++i)
        ((float4v*)WgS)[tid + i * 256] = ((const float4v*)Wg)[tid + i * 256];
    __syncthreads();

    int q = tid & 7, tg = tid >> 3;                   // 32 groups x 2 tokens = 64 tokens/block
    int t0 = blockIdx.x * 64 + tg * 2;

    float acc[2][16];
#pragma unroll
    for (int tt = 0; tt < 2; ++tt)
#pragma unroll
        for (int e = 0; e < 16; ++e) acc[tt][e] = 0.f;

#pragma unroll
    for (int ii = 0; ii < 8; ++ii) {                  // K-eighth: 32 floats = 8 float4
        int kb = q * 32 + ii * 4;
        float4v xv[2];
#pragma unroll
        for (int tt = 0; tt < 2; ++tt) {
            xv[tt] = *(const float4v*)&x[(t0 + tt) * DIN + kb];
            half4v hv;
#pragma unroll
            for (int j = 0; j < 4; ++j) hv[j] = (_Float16)xv[tt][j];
            *(half4v*)&xh[(t0 + tt) * DIN + kb] = hv;
        }
#pragma unroll
        for (int j = 0; j < 4; ++j) {
            const float4v* wrow = (const float4v*)&WgS[(kb + j) * 16];
            float4v w0 = wrow[0], w1 = wrow[1], w2 = wrow[2], w3 = wrow[3];
#pragma unroll
            for (int tt = 0; tt < 2; ++tt) {
                float xs = xv[tt][j];
#pragma unroll
                for (int c = 0; c < 4; ++c) {
                    acc[tt][0 + c]  += xs * w0[c];
                    acc[tt][4 + c]  += xs * w1[c];
                    acc[tt][8 + c]  += xs * w2[c];
                    acc[tt][12 + c] += xs * w3[c];
                }
            }
        }
    }
#pragma unroll
    for (int tt = 0; tt < 2; ++tt)
#pragma unroll
        for (int e = 0; e < 16; ++e) {
            acc[tt][e] += __shfl_xor(acc[tt][e], 1);
            acc[tt][e] += __shfl_xor(acc[tt][e], 2);
            acc[tt][e] += __shfl_xor(acc[tt][e], 4);
        }
    if (q == 0) {
#pragma unroll
        for (int tt = 0; tt < 2; ++tt) {
            int b = t0 + tt;
            float m1 = -3.4e38f, m2 = -3.4e38f;
            int i1 = 0, i2 = 0;
#pragma unroll
            for (int e = 0; e < 16; ++e) {
                float v = acc[tt][e] + bg[e];
                if (v > m1) { m2 = m1; i2 = i1; m1 = v; i1 = e; }
                else if (v > m2) { m2 = v; i2 = e; }
            }
            float e2 = __expf(m2 - m1);
            float w1 = 1.f / (1.f + e2);
            tidx[b * 2] = i1; tidx[b * 2 + 1] = i2;
            tw[b * 2] = w1;  tw[b * 2 + 1] = e2 * w1;
            atomicAdd(&hcnt[i1], 1);
            atomicAdd(&hcnt[i2], 1);
        }
    }
    __syncthreads();
    if (tid < 16) atomicAdd(&counts[tid], hcnt[tid]);
}

// ---------------- scan + XCD-affine tile map (parallel fill) ----------------
// expert e's tiles land at blockIdx ≡ e (mod 8); slot base: e<8 -> 0, e>=8 -> tiles(e-8).
__global__ void scan_kernel(const int* __restrict__ counts, int* __restrict__ offsets,
                            int* __restrict__ cursor, int* __restrict__ tmap) {
    __shared__ int s_off[17];
    int tid = threadIdx.x;
    for (int i = tid; i < MLP_GRID; i += 64) tmap[i] = -1;
    if (tid == 0) {
        int run = 0;
        for (int e = 0; e < 16; ++e) { s_off[e] = run; run += counts[e]; }
        s_off[16] = run;
    }
    __syncthreads();
    if (tid < 16) {
        int e = tid;
        offsets[e] = s_off[e];
        cursor[e] = s_off[e];
        if (e == 0) offsets[16] = s_off[16];
        int nt = (s_off[e + 1] - s_off[e] + 63) >> 6;
        int xc = e & 7;
        int base = (e >= 8) ? ((s_off[e - 7] - s_off[e - 8] + 63) >> 6) : 0;
        for (int t = 0; t < nt; ++t) {
            int s = base + t;
            if (s < 256) tmap[xc + 8 * s] = (e << 16) | t;
        }
    }
}

// ---------------- scatter: block-ranked, 16 global atomics per block ----------------
__global__ __launch_bounds__(256) void scatter_kernel(const int* __restrict__ tidx,
                                                      const float* __restrict__ tw,
                                                      int* __restrict__ cursor,
                                                      int* __restrict__ stok,
                                                      float* __restrict__ sw) {
    __shared__ int lc[16];
    __shared__ int lbase[16];
    int tid = threadIdx.x;
    if (tid < 16) lc[tid] = 0;
    __syncthreads();
    int g = blockIdx.x * 256 + tid;
    int e = tidx[g];
    int rank = atomicAdd(&lc[e], 1);
    __syncthreads();
    if (tid < 16) lbase[tid] = atomicAdd(&cursor[tid], lc[tid]);
    __syncthreads();
    int pos = lbase[e] + rank;
    stok[pos] = g;                 // g = tok*2 + slot
    sw[pos] = tw[g];
}

// ---------------- fused expert MLP ----------------
// LDS: Xs 64x256 halfs (32 KB, swizzled) + Hs 64x256 halfs (32 KB, swizzled) = 64 KB
// Phase 1/2 split over two DH-halves; X staged once; weights stream from XCD-local L2.
#define XS 0
#define HS 16384
__global__ __launch_bounds__(512, 4) void mlp_kernel(const _Float16* __restrict__ xh,
                                                     const _Float16* __restrict__ p1,
                                                     const _Float16* __restrict__ p2,
                                                     const float* __restrict__ b1,
                                                     const float* __restrict__ b2,
                                                     const int* __restrict__ offsets,
                                                     const int* __restrict__ stok,
                                                     const float* __restrict__ sw,
                                                     const int* __restrict__ tmap,
                                                     _Float16* __restrict__ scr) {
    __shared__ _Float16 S[32768];                     // 64 KB
    const int tile = tmap[blockIdx.x];
    if (tile < 0) return;
    const int e = tile >> 16;
    const int ts = (tile & 0xffff) * 64;
    const int off = offsets[e];
    const int ne = offsets[e + 1] - off;
    const int rows = min(64, ne - ts);

    const int tid = threadIdx.x;
    const int w = tid >> 6;                           // wave 0..7
    const int l = tid & 63;
    const int l15 = l & 15;
    const int quad = l >> 4;

    // ---- stage X tile (64 tok x 256 halfs) into LDS, 16B-granule XOR swizzle ----
#pragma unroll
    for (int j = 0; j < 4; ++j) {
        int tokl = w * 8 + j * 2 + (l >> 5);          // local token row
        int slot = l & 31;                            // 16B slot within row
        int g = slot ^ (tokl & 7);                    // logical k-granule stored here
        int r = tokl; if (r >= rows) r = rows - 1;
        int tok = stok[off + ts + r] >> 1;
        half8 v = *(const half8*)&xh[tok * DIN + g * 8];
        *(half8*)&S[XS + tokl * 256 + slot * 8] = v;
    }

    const half8* p1b = (const half8*)p1;
    const half8* p2b = (const half8*)p2;

    float4v acc2[4][2];
#pragma unroll
    for (int mt = 0; mt < 4; ++mt)
#pragma unroll
        for (int n = 0; n < 2; ++n) acc2[mt][n] = (float4v){0.f, 0.f, 0.f, 0.f};

    __syncthreads();

#pragma unroll
    for (int half = 0; half < 2; ++half) {
        // ---- phase 1: H[:, half*256 .. half*256+255] ; wave w owns h-tiles w*2, w*2+1 ----
        float4v acc1[2][4];
#pragma unroll
        for (int mh = 0; mh < 2; ++mh)
#pragma unroll
            for (int nt = 0; nt < 4; ++nt) acc1[mh][nt] = (float4v){0.f, 0.f, 0.f, 0.f};

#pragma unroll
        for (int kt = 0; kt < 8; ++kt) {
            half8 bq[4];
#pragma unroll
            for (int nt = 0; nt < 4; ++nt) {
                int row = nt * 16 + l15;
                int slot = (kt * 4 + quad) ^ (l15 & 7);
                bq[nt] = *(const half8*)&S[XS + row * 256 + slot * 8];
            }
#pragma unroll
            for (int mh = 0; mh < 2; ++mh) {
                half8 aw = p1b[((e * 8 + kt) * 32 + half * 16 + w * 2 + mh) * 64 + l];
#pragma unroll
                for (int nt = 0; nt < 4; ++nt)
                    acc1[mh][nt] = __builtin_amdgcn_mfma_f32_16x16x32_f16(aw, bq[nt], acc1[mh][nt], 0, 0, 0);
            }
        }
        // bias + relu + store H-half (half4 per acc tile, swizzled)
#pragma unroll
        for (int mh = 0; mh < 2; ++mh) {
            int colh = (w * 2 + mh) * 16 + quad * 4;  // local h col (0..255)
            float4v b1q = *(const float4v*)&b1[e * DH + half * 256 + colh];
            int gq = colh >> 3;                       // 16B granule
            int go = (quad & 1) * 4;                  // half offset within granule
#pragma unroll
            for (int nt = 0; nt < 4; ++nt) {
                int row = nt * 16 + l15;
                int slot = gq ^ (l15 & 7);
                half4v hv;
#pragma unroll
                for (int r = 0; r < 4; ++r) {
                    float v = acc1[mh][nt][r] + b1q[r];
                    hv[r] = (_Float16)(v > 0.f ? v : 0.f);
                }
                *(half4v*)&S[HS + row * 256 + slot * 8 + go] = hv;
            }
        }
        __syncthreads();

        // ---- phase 2 partial: acc2 += H_half @ W2[half*256.., :] ----
#pragma unroll
        for (int kt2 = 0; kt2 < 8; ++kt2) {
            half8 ha[4];
#pragma unroll
            for (int mt = 0; mt < 4; ++mt) {
                int row = mt * 16 + l15;
                int slot = (kt2 * 4 + quad) ^ (l15 & 7);
                ha[mt] = *(const half8*)&S[HS + row * 256 + slot * 8];
            }
#pragma unroll
            for (int n = 0; n < 2; ++n) {
                half8 bw = p2b[((e * 16 + half * 8 + kt2) * 16 + w * 2 + n) * 64 + l];
#pragma unroll
                for (int mt = 0; mt < 4; ++mt)
                    acc2[mt][n] = __builtin_amdgcn_mfma_f32_16x16x32_f16(ha[mt], bw, acc2[mt][n], 0, 0, 0);
            }
        }
        __syncthreads();                              // H reads done before overwrite / reuse
    }

    // ---- epilogue: +b2, routing weight, transpose through LDS (reuse Hs), coalesced store ----
    float b2v[2];
#pragma unroll
    for (int n = 0; n < 2; ++n) b2v[n] = b2[e * DOUT + (w * 2 + n) * 16 + l15];
#pragma unroll
    for (int mt = 0; mt < 4; ++mt) {
#pragma unroll
        for (int r = 0; r < 4; ++r) {
            int row = mt * 16 + quad * 4 + r;         // token row of this acc element
            int rc = row < rows ? row : rows - 1;
            float wt = sw[off + ts + rc];
#pragma unroll
            for (int n = 0; n < 2; ++n) {
                int col = (w * 2 + n) * 16 + l15;     // out col 0..255
                int slot = (col >> 3) ^ (row & 7);
                S[HS + row * 256 + slot * 8 + (col & 7)] =
                    (_Float16)(wt * (acc2[mt][n][r] + b2v[n]));
            }
        }
    }
    __syncthreads();
#pragma unroll
    for (int p = 0; p < 4; ++p) {
        int idx = p * 512 + tid;
        int tok = idx >> 5;                           // local token row
        int sl = idx & 31;                            // logical 16B granule
        if (tok < rows) {
            int slot = sl ^ (tok & 7);
            half8 v = *(const half8*)&S[HS + tok * 256 + slot * 8];
            int g = stok[off + ts + tok];             // assignment slot = tok*2+sel
            *(half8*)&scr[g * DOUT + sl * 8] = v;
        }
    }
}

// ---------------- combine: out[t] = scr[t*2] + scr[t*2+1], streaming ----------------
__global__ __launch_bounds__(256) void combine_kernel(const _Float16* __restrict__ scr,
                                                      float* __restrict__ out) {
    int wv = threadIdx.x >> 6;
    int l = threadIdx.x & 63;
    int t = blockIdx.x * 4 + wv;
    half4v a = ((const half4v*)(scr + t * 2 * DOUT))[l];
    half4v b = ((const half4v*)(scr + t * 2 * DOUT + DOUT))[l];
    float4v o;
#pragma unroll
    for (int j = 0; j < 4; ++j) o[j] = (float)a[j] + (float)b[j];
    ((float4v*)(out + t * DOUT))[l] = o;
}

extern "C" void kernel_launch(void* const* d_in, const int* in_sizes, int n_in,
                              void* d_out, int out_size, void* d_ws, size_t ws_size,
                              hipStream_t stream) {
    const float* x  = (const float*)d_in[0];
    const float* Wg = (const float*)d_in[1];
    const float* bg = (const float*)d_in[2];
    const float* W1 = (const float*)d_in[3];
    const float* b1 = (const float*)d_in[4];
    const float* W2 = (const float*)d_in[5];
    const float* b2 = (const float*)d_in[6];
    float* out = (float*)d_out;

    char* ws = (char*)d_ws;
    _Float16* p1  = (_Float16*)(ws + OFF_P1);
    _Float16* p2  = (_Float16*)(ws + OFF_P2);
    _Float16* xh  = (_Float16*)(ws + OFF_XH);
    _Float16* scr = (_Float16*)(ws + OFF_SCR);
    int* tidx     = (int*)(ws + OFF_TIDX);
    float* tw     = (float*)(ws + OFF_TW);
    int* stok     = (int*)(ws + OFF_STOK);
    float* swp    = (float*)(ws + OFF_SW);
    int* counts   = (int*)(ws + OFF_CNT);
    int* offsets  = (int*)(ws + OFF_OFFS);
    int* cursor   = (int*)(ws + OFF_CUR);
    int* tmap     = (int*)(ws + OFF_TMAP);

    pack_kernel<<<dim3(2048), dim3(256), 0, stream>>>(W1, W2, p1, p2, counts);
    gate_kernel<<<dim3(512), dim3(256), 0, stream>>>(x, Wg, bg, xh, tidx, tw, counts);
    scan_kernel<<<dim3(1), dim3(64), 0, stream>>>(counts, offsets, cursor, tmap);
    scatter_kernel<<<dim3(256), dim3(256), 0, stream>>>(tidx, tw, cursor, stok, swp);
    mlp_kernel<<<dim3(MLP_GRID), dim3(512), 0, stream>>>(xh, p1, p2, b1, b2, offsets,
                                                         stok, swp, tmap, scr);
    combine_kernel<<<dim3(8192), dim3(256), 0, stream>>>(scr, out);
}